// Round 8
// baseline (21222.740 us; speedup 1.0000x reference)
//
#include <hip/hip_runtime.h>
#include <math.h>

#define NTHR 1024

// per-batch global e-buffers (floats)
constexpr int E1_OFF  = 0;          // level 1: 128 rows x 128
constexpr int E2_OFF  = 16384;      // level 2: 64 rows
constexpr int E3_OFF  = 24576;      // level 3: 32 rows
constexpr int E4_OFF  = 28672;      // level 4: 16 rows
constexpr int EG_STRIDE = 30720;    // floats per batch

__device__ __forceinline__ int xoff(int l) { return 512 - (512 >> l); }   // l in 0..7
// LDS e-levels 5..8 offsets (floats): rows 8,4,2,1(+pad)
__device__ __forceinline__ int ldse(int l) {
  return (l == 5) ? 0 : (l == 6) ? 1024 : (l == 7) ? 1536 : 1792;
}

// ---- one MLP chunk: eout = relu(z@W1+b1 [+lab]) @ W2 + b2 ----------------
// 16 waves = 16 K-slices of 16k (both layers). L1: lane owns 4 cols; L2: 2.
// Each phase preloads its ENTIRE weight slice into registers first (16
// independent loads in flight -> one latency exposure), then row-loops with
// a tiny live set (acc = 1 float4). Weights read exactly once per chunk.
template <int C, bool ZG>
__device__ __forceinline__ void mlp_chunk(
    const float* __restrict__ zg, const float* zl, int zstr,
    const float* __restrict__ W1, const float* __restrict__ B1,
    const float* __restrict__ W2, const float* __restrict__ B2,
    const float* lab, bool uselab, const int* u1h, int done,
    float* red, float* h, float* eoutL, float* __restrict__ eoutG)
{
  const int t  = threadIdx.x;
  const int wv = t >> 6;          // K-slice 0..15  (k in [16wv,16wv+16))
  const int ln = t & 63;
  // -------- layer-1 partials --------
  {
    const int k0 = 16 * wv;
    const int c0 = 4 * ln;
    float4 w[16];
#pragma unroll
    for (int j = 0; j < 16; ++j)
      w[j] = *reinterpret_cast<const float4*>(W1 + (k0 + j) * 256 + c0);
#pragma unroll 1
    for (int r = 0; r < C; ++r) {
      float2 z2[8];
#pragma unroll
      for (int j = 0; j < 8; ++j) {
        if (ZG) z2[j] = *reinterpret_cast<const float2*>(zg + r * zstr + k0 + 2 * j);
        else    z2[j] = *reinterpret_cast<const float2*>(zl + r * zstr + k0 + 2 * j);
      }
      float4 acc = make_float4(0.f, 0.f, 0.f, 0.f);
#pragma unroll
      for (int j = 0; j < 8; ++j) {
        acc.x = fmaf(z2[j].x, w[2*j].x, fmaf(z2[j].y, w[2*j+1].x, acc.x));
        acc.y = fmaf(z2[j].x, w[2*j].y, fmaf(z2[j].y, w[2*j+1].y, acc.y));
        acc.z = fmaf(z2[j].x, w[2*j].z, fmaf(z2[j].y, w[2*j+1].z, acc.z));
        acc.w = fmaf(z2[j].x, w[2*j].w, fmaf(z2[j].y, w[2*j+1].w, acc.w));
      }
      *reinterpret_cast<float4*>(red + (wv * C + r) * 256 + c0) = acc;
    }
  }
  __syncthreads();
  // -------- layer-1 reduce + bias + lab + relu -> h --------
  if (t < 64 * C) {
    const int r  = t >> 6;
    const int c0 = 4 * (t & 63);
    float4 s = *reinterpret_cast<const float4*>(B1 + c0);
    if (uselab) {
      const int j = u1h[done + r] & 1;
      const float4 lv = *reinterpret_cast<const float4*>(lab + j * 256 + c0);
      s.x += lv.x; s.y += lv.y; s.z += lv.z; s.w += lv.w;
    }
#pragma unroll
    for (int q = 0; q < 16; ++q) {
      const float4 p = *reinterpret_cast<const float4*>(red + (q * C + r) * 256 + c0);
      s.x += p.x; s.y += p.y; s.z += p.z; s.w += p.w;
    }
    s.x = fmaxf(s.x, 0.f); s.y = fmaxf(s.y, 0.f);
    s.z = fmaxf(s.z, 0.f); s.w = fmaxf(s.w, 0.f);
    *reinterpret_cast<float4*>(h + r * 256 + c0) = s;
  }
  __syncthreads();
  // -------- layer-2 partials --------
  {
    const int k0 = 16 * wv;
    const int c0 = 2 * ln;
    float2 w[16];
#pragma unroll
    for (int j = 0; j < 16; ++j)
      w[j] = *reinterpret_cast<const float2*>(W2 + (k0 + j) * 128 + c0);
#pragma unroll 1
    for (int r = 0; r < C; ++r) {
      float4 h4[4];
#pragma unroll
      for (int j = 0; j < 4; ++j)
        h4[j] = *reinterpret_cast<const float4*>(h + r * 256 + k0 + 4 * j);
      float2 acc = make_float2(0.f, 0.f);
#pragma unroll
      for (int j = 0; j < 4; ++j) {
        acc.x = fmaf(h4[j].x, w[4*j+0].x, fmaf(h4[j].y, w[4*j+1].x,
                fmaf(h4[j].z, w[4*j+2].x, fmaf(h4[j].w, w[4*j+3].x, acc.x))));
        acc.y = fmaf(h4[j].x, w[4*j+0].y, fmaf(h4[j].y, w[4*j+1].y,
                fmaf(h4[j].z, w[4*j+2].y, fmaf(h4[j].w, w[4*j+3].y, acc.y))));
      }
      *reinterpret_cast<float2*>(red + (wv * C + r) * 128 + c0) = acc;
    }
  }
  __syncthreads();
  // -------- layer-2 reduce + bias -> eout --------
  if (t < 128 * C) {
    const int r = t >> 7;
    const int c = t & 127;
    float s = B2[c];
#pragma unroll
    for (int q = 0; q < 16; ++q) s += red[(q * C + r) * 128 + c];
    if (eoutL) eoutL[r * 128 + c] = s;
    else       eoutG[r * 128 + c] = s;
  }
  __syncthreads();
}

__global__ void sc_setup(const int* __restrict__ info_set,
                         const float* __restrict__ E_obs,
                         const float* __restrict__ E_lab,
                         const float* __restrict__ Wb1,
                         int* __restrict__ pos2k, float* __restrict__ lab1,
                         float* __restrict__ eroot)
{
  const int t = threadIdx.x;   // 256 threads
  pos2k[t] = -1;
  __syncthreads();
  if (t < 128) pos2k[info_set[t]] = t;
  eroot[t] = E_obs[2 * 128 + (t & 127)];
  for (int j = 0; j < 2; ++j) {
    float s = 0.0f;
    for (int k = 0; k < 128; ++k)
      s = fmaf(E_lab[j * 128 + k], Wb1[(256 + k) * 256 + t], s);
    lab1[j * 256 + t] = s;
  }
}

__global__ __launch_bounds__(NTHR, 4)
void sc_main(const int* __restrict__ info_bits, const float* __restrict__ rin,
             const float* __restrict__ Wc1, const float* __restrict__ bc1,
             const float* __restrict__ Wc2, const float* __restrict__ bc2,
             const float* __restrict__ Wb1, const float* __restrict__ bb1,
             const float* __restrict__ Wb2, const float* __restrict__ bb2,
             const float* __restrict__ Wl, const float* __restrict__ bl,
             const int* __restrict__ pos2k, const float* __restrict__ lab1_g,
             const float* __restrict__ eroot_g,
             float* __restrict__ wsall, float* __restrict__ out)
{
  const int b = blockIdx.x;
  const int t = threadIdx.x;
  float* eg = wsall + (size_t)b * EG_STRIDE;   // levels 1..4 (global)

  __shared__ float red[32768];      // 128 KB split-K partials
  __shared__ float h_lds[2048];     //   8 KB hidden
  __shared__ float e_lds[2048];     //   8 KB e-levels 5..8 (+pad)
  __shared__ float lab_lds[512];
  __shared__ float eroot[256];
  __shared__ int   xh[520];         // +8 pad (padded-row u1h reads)

  for (int idx = t; idx < 512; idx += NTHR) lab_lds[idx] = lab1_g[idx];
  if (t < 256) eroot[t] = eroot_g[t];
  if (t >= 512 && t < 520) xh[t] = 0;
  __syncthreads();

  float* xO = out;
  float* fO = out + 32768;
  float* uO = out + 65536;
  float* pO = out + 98304;
  float* rO = out + 131072;

  auto run_level = [&](int l, bool isbit) {
    const int rows = 128 >> l;
    const float* W1 = isbit ? Wb1 : Wc1;
    const float* B1 = isbit ? bb1 : bc1;
    const float* W2 = isbit ? Wb2 : Wc2;
    const float* B2 = isbit ? bb2 : bc2;
    const int* u1h = xh + xoff(l);
    const float* zg = nullptr; const float* zl = nullptr;
    int zstr = 256; bool isZG = false;
    float* eoL = nullptr; float* eoG = nullptr;
    switch (l) {
      case 0: zl = eroot; zstr = 0;            eoG = eg + E1_OFF; break;
      case 1: zg = eg + E1_OFF; isZG = true;   eoG = eg + E2_OFF; break;
      case 2: zg = eg + E2_OFF; isZG = true;   eoG = eg + E3_OFF; break;
      case 3: zg = eg + E3_OFF; isZG = true;   eoG = eg + E4_OFF; break;
      case 4: zg = eg + E4_OFF; isZG = true;   eoL = e_lds + ldse(5); break;
      case 5: zl = e_lds + ldse(5);            eoL = e_lds + ldse(6); break;
      case 6: zl = e_lds + ldse(6);            eoL = e_lds + ldse(7); break;
      default: zl = e_lds + ldse(7);           eoL = e_lds + ldse(8); break;
    }
    int done = 0;
    while (done < rows) {
      int c = rows - done;
      if (c > 8) c = 8;
      const float* zgc = zg ? zg + done * zstr : nullptr;
      const float* zlc = zl ? zl + done * zstr : nullptr;
      float* eoLc = eoL ? eoL + done * 128 : nullptr;
      float* eoGc = eoG ? eoG + done * 128 : nullptr;
      if (c == 8) {
        if (isZG) mlp_chunk<8, true >(zgc, zlc, zstr, W1, B1, W2, B2, lab_lds, isbit, u1h, done, red, h_lds, eoLc, eoGc);
        else      mlp_chunk<8, false>(zgc, zlc, zstr, W1, B1, W2, B2, lab_lds, isbit, u1h, done, red, h_lds, eoLc, eoGc);
      } else if (c == 4) {
        if (isZG) mlp_chunk<4, true >(zgc, zlc, zstr, W1, B1, W2, B2, lab_lds, isbit, u1h, done, red, h_lds, eoLc, eoGc);
        else      mlp_chunk<4, false>(zgc, zlc, zstr, W1, B1, W2, B2, lab_lds, isbit, u1h, done, red, h_lds, eoLc, eoGc);
      } else {    // c == 2 or 1 -> padded C=2
        if (isZG) mlp_chunk<2, true >(zgc, zlc, zstr, W1, B1, W2, B2, lab_lds, isbit, u1h, done, red, h_lds, eoLc, eoGc);
        else      mlp_chunk<2, false>(zgc, zlc, zstr, W1, B1, W2, B2, lab_lds, isbit, u1h, done, red, h_lds, eoLc, eoGc);
      }
      done += c;
    }
  };

  auto do_leaf = [&](int i) {
    const float* e = e_lds + ldse(8);
    if (t < 64) {
      float partial = e[t] * Wl[t] + e[t + 64] * Wl[t + 64];
#pragma unroll
      for (int m = 32; m >= 1; m >>= 1) partial += __shfl_xor(partial, m);
      if (t == 0) {
        const float tv = partial + bl[0];
        const float p  = 1.0f / (1.0f + expf(-tv));
        const float rv = rin[b * 256 + i];
        const int  hd     = (rv > p) ? 1 : 0;
        const bool frozen = fabsf(p - 0.5f) > 0.25f;
        const int  k  = pos2k[i];
        const int  fc = (k >= 0) ? info_bits[b * 128 + k] : 2;
        const int  x  = (fc == 2 || frozen) ? hd : fc;
        xh[xoff(7) + (i & 1)] = x;
        pO[b * 256 + i] = p;
        uO[b * 256 + i] = (float)x;
        fO[b * 256 + i] = (k >= 0) ? 2.0f : 1.0f;
        rO[b * 256 + i] = rv;
      }
    }
    __syncthreads();
  };
  auto do_combine = [&](int l, int side) {
    const int n = 256 >> l, half = n >> 1;
    if (t < half) {
      const int u1 = xh[xoff(l) + t];
      const int u2 = xh[xoff(l) + half + t];
      if (l > 0) {
        const int base = xoff(l - 1) + side * n;
        xh[base + 2 * t]     = u1 ^ u2;
        xh[base + 2 * t + 1] = u2;
      } else {
        xO[b * 256 + 2 * t]     = (float)(u1 ^ u2);
        xO[b * 256 + 2 * t + 1] = (float)u2;
      }
    }
    __syncthreads();
  };

  // ---- SC traversal, single stage call-site ----
  int i = 0, l = 0;
  bool isbit = false;
  while (true) {
    run_level(l, isbit);
    if (l < 7) { ++l; isbit = false; continue; }
    do_leaf(i);
    if (i == 255) break;
    ++i;
    const int s = __builtin_ctz(i);
    for (int j = 1; j <= s; ++j) do_combine(8 - j, (j < s) ? 1 : 0);
    l = 7 - s;
    isbit = true;
  }
  for (int j = 1; j <= 8; ++j) do_combine(8 - j, 1);
}

extern "C" void kernel_launch(void* const* d_in, const int* in_sizes, int n_in,
                              void* d_out, int out_size, void* d_ws, size_t ws_size,
                              hipStream_t stream)
{
  const int*   info_bits = (const int*)  d_in[0];
  const float* rin       = (const float*)d_in[1];
  const int*   info_set  = (const int*)  d_in[2];
  const float* E_obs     = (const float*)d_in[3];
  const float* E_lab     = (const float*)d_in[4];
  const float* Wc1 = (const float*)d_in[5];
  const float* bc1 = (const float*)d_in[6];
  const float* Wc2 = (const float*)d_in[7];
  const float* bc2 = (const float*)d_in[8];
  const float* Wb1 = (const float*)d_in[9];
  const float* bb1 = (const float*)d_in[10];
  const float* Wb2 = (const float*)d_in[11];
  const float* bb2 = (const float*)d_in[12];
  const float* Wl  = (const float*)d_in[13];
  const float* bl  = (const float*)d_in[14];

  int*   pos2k = (int*)d_ws;                 // 256 ints
  float* lab1  = (float*)d_ws + 256;         // 512 floats
  float* eroot = (float*)d_ws + 768;         // 256 floats
  float* wsall = (float*)d_ws + 1024;        // 128 x EG_STRIDE floats

  hipLaunchKernelGGL(sc_setup, dim3(1), dim3(256), 0, stream,
                     info_set, E_obs, E_lab, Wb1, pos2k, lab1, eroot);
  hipLaunchKernelGGL(sc_main, dim3(128), dim3(NTHR), 0, stream,
                     info_bits, rin,
                     Wc1, bc1, Wc2, bc2, Wb1, bb1, Wb2, bb2, Wl, bl,
                     pos2k, lab1, eroot, wsall, (float*)d_out);
}

// Round 9
// 11134.163 us; speedup vs baseline: 1.9061x; 1.9061x over previous
//
#include <hip/hip_runtime.h>
#include <math.h>

#define NTHR 512

// per-batch global e-buffers (floats)
constexpr int E1_OFF  = 0;          // level 1: 128 rows x 128
constexpr int E2_OFF  = 16384;      // level 2: 64 rows
constexpr int E3_OFF  = 24576;      // level 3: 32 rows
constexpr int E4_OFF  = 28672;      // level 4: 16 rows
constexpr int EG_STRIDE = 30720;    // floats per batch

__device__ __forceinline__ int xoff(int l) { return 512 - (512 >> l); }   // l in 0..7
// LDS e-levels 5..8 offsets (floats): rows 8,4,2,1
__device__ __forceinline__ int ldse(int l) {
  return (l == 5) ? 0 : (l == 6) ? 1024 : (l == 7) ? 1536 : 1792;
}

// ---- one MLP chunk (up to 32 rows): eout = relu(z@W1+b1 [+lab]) @ W2 + b2
// 8 waves = 8 K-slices of 32 k. L1: lane owns 4 cols, w1[32] float4 resident
// (128 VGPRs, 32 independent b128 loads in flight -> weight stream at BW).
// L2: lane owns 2 cols, w2[32] float2 resident. Rows loop dynamically;
// acc is a single float4/float2; cross-wave reduce via red in rowblocks of 8.
// All z/h reads are wave-uniform LDS broadcasts.
__device__ __forceinline__ void mlp_chunk(
    const float* zsrc, int zstr, int C,
    const float* __restrict__ W1, const float* __restrict__ B1,
    const float* __restrict__ W2, const float* __restrict__ B2,
    const float* lab, bool uselab, const int* u1h, int done,
    float* red, float* h, float* eoutL, float* __restrict__ eoutG)
{
  const int t  = threadIdx.x;       // 0..511
  const int wv = t >> 6;            // K-slice 0..7
  const int ln = t & 63;
  // ---------------- layer 1 ----------------
  {
    const int k0 = 32 * wv;
    const int c0 = 4 * ln;
    float4 w[32];
#pragma unroll
    for (int j = 0; j < 32; ++j)
      w[j] = *reinterpret_cast<const float4*>(W1 + (k0 + j) * 256 + c0);
    int rbase = 0;
    while (rbase < C) {
      const int rn = (C - rbase < 8) ? (C - rbase) : 8;
#pragma unroll 1
      for (int rr = 0; rr < rn; ++rr) {
        const float* zp = zsrc + (rbase + rr) * zstr + k0;
        float4 z4[8];
#pragma unroll
        for (int j = 0; j < 8; ++j) z4[j] = *reinterpret_cast<const float4*>(zp + 4 * j);
        float4 acc = make_float4(0.f, 0.f, 0.f, 0.f);
#pragma unroll
        for (int j = 0; j < 8; ++j) {
          acc.x = fmaf(z4[j].x, w[4*j+0].x, fmaf(z4[j].y, w[4*j+1].x,
                  fmaf(z4[j].z, w[4*j+2].x, fmaf(z4[j].w, w[4*j+3].x, acc.x))));
          acc.y = fmaf(z4[j].x, w[4*j+0].y, fmaf(z4[j].y, w[4*j+1].y,
                  fmaf(z4[j].z, w[4*j+2].y, fmaf(z4[j].w, w[4*j+3].y, acc.y))));
          acc.z = fmaf(z4[j].x, w[4*j+0].z, fmaf(z4[j].y, w[4*j+1].z,
                  fmaf(z4[j].z, w[4*j+2].z, fmaf(z4[j].w, w[4*j+3].z, acc.z))));
          acc.w = fmaf(z4[j].x, w[4*j+0].w, fmaf(z4[j].y, w[4*j+1].w,
                  fmaf(z4[j].z, w[4*j+2].w, fmaf(z4[j].w, w[4*j+3].w, acc.w))));
        }
        *reinterpret_cast<float4*>(red + (wv * 8 + rr) * 256 + c0) = acc;
      }
      __syncthreads();
      {   // reduce rowblock: thread -> (r = t>>6, 4 cols)
        const int r  = t >> 6;
        const int cc = 4 * (t & 63);
        if (r < rn) {
          float4 s = *reinterpret_cast<const float4*>(B1 + cc);
          if (uselab) {
            const int j = u1h[done + rbase + r] & 1;
            const float4 lv = *reinterpret_cast<const float4*>(lab + j * 256 + cc);
            s.x += lv.x; s.y += lv.y; s.z += lv.z; s.w += lv.w;
          }
#pragma unroll
          for (int q = 0; q < 8; ++q) {
            const float4 p = *reinterpret_cast<const float4*>(red + (q * 8 + r) * 256 + cc);
            s.x += p.x; s.y += p.y; s.z += p.z; s.w += p.w;
          }
          s.x = fmaxf(s.x, 0.f); s.y = fmaxf(s.y, 0.f);
          s.z = fmaxf(s.z, 0.f); s.w = fmaxf(s.w, 0.f);
          *reinterpret_cast<float4*>(h + (rbase + r) * 256 + cc) = s;
        }
      }
      __syncthreads();
      rbase += rn;
    }
  }
  // ---------------- layer 2 ----------------
  {
    const int k0 = 32 * wv;
    const int c0 = 2 * ln;
    float2 w[32];
#pragma unroll
    for (int j = 0; j < 32; ++j)
      w[j] = *reinterpret_cast<const float2*>(W2 + (k0 + j) * 128 + c0);
    int rbase = 0;
    while (rbase < C) {
      const int rn = (C - rbase < 8) ? (C - rbase) : 8;
#pragma unroll 1
      for (int rr = 0; rr < rn; ++rr) {
        const float* hp = h + (rbase + rr) * 256 + k0;
        float4 h4[8];
#pragma unroll
        for (int j = 0; j < 8; ++j) h4[j] = *reinterpret_cast<const float4*>(hp + 4 * j);
        float2 acc = make_float2(0.f, 0.f);
#pragma unroll
        for (int j = 0; j < 8; ++j) {
          acc.x = fmaf(h4[j].x, w[4*j+0].x, fmaf(h4[j].y, w[4*j+1].x,
                  fmaf(h4[j].z, w[4*j+2].x, fmaf(h4[j].w, w[4*j+3].x, acc.x))));
          acc.y = fmaf(h4[j].x, w[4*j+0].y, fmaf(h4[j].y, w[4*j+1].y,
                  fmaf(h4[j].z, w[4*j+2].y, fmaf(h4[j].w, w[4*j+3].y, acc.y))));
        }
        *reinterpret_cast<float2*>(red + (wv * 8 + rr) * 128 + c0) = acc;
      }
      __syncthreads();
      {
        const int r = t >> 6;
        const int c = 2 * (t & 63);
        if (r < rn) {
          float2 s = make_float2(B2[c], B2[c + 1]);
#pragma unroll
          for (int q = 0; q < 8; ++q) {
            const float2 p = *reinterpret_cast<const float2*>(red + (q * 8 + r) * 128 + c);
            s.x += p.x; s.y += p.y;
          }
          const int o = (rbase + r) * 128 + c;
          if (eoutL) *reinterpret_cast<float2*>(eoutL + o) = s;
          else       *reinterpret_cast<float2*>(eoutG + o) = s;
        }
      }
      __syncthreads();
      rbase += rn;
    }
  }
}

__global__ void sc_setup(const int* __restrict__ info_set,
                         const float* __restrict__ E_obs,
                         const float* __restrict__ E_lab,
                         const float* __restrict__ Wb1,
                         int* __restrict__ pos2k, float* __restrict__ lab1,
                         float* __restrict__ eroot)
{
  const int t = threadIdx.x;   // 256 threads
  pos2k[t] = -1;
  __syncthreads();
  if (t < 128) pos2k[info_set[t]] = t;
  eroot[t] = E_obs[2 * 128 + (t & 127)];
  for (int j = 0; j < 2; ++j) {
    float s = 0.0f;
    for (int k = 0; k < 128; ++k)
      s = fmaf(E_lab[j * 128 + k], Wb1[(256 + k) * 256 + t], s);
    lab1[j * 256 + t] = s;
  }
}

__global__ __launch_bounds__(NTHR, 1)
void sc_main(const int* __restrict__ info_bits, const float* __restrict__ rin,
             const float* __restrict__ Wc1, const float* __restrict__ bc1,
             const float* __restrict__ Wc2, const float* __restrict__ bc2,
             const float* __restrict__ Wb1, const float* __restrict__ bb1,
             const float* __restrict__ Wb2, const float* __restrict__ bb2,
             const float* __restrict__ Wl, const float* __restrict__ bl,
             const int* __restrict__ pos2k, const float* __restrict__ lab1_g,
             const float* __restrict__ eroot_g,
             float* __restrict__ wsall, float* __restrict__ out)
{
  const int b = blockIdx.x;
  const int t = threadIdx.x;
  float* eg = wsall + (size_t)b * EG_STRIDE;   // levels 1..4 (global)

  __shared__ float red[16384];      // 64 KB split-K partials
  __shared__ float h_lds[8192];     // 32 KB hidden (up to 32 rows)
  __shared__ float z_lds[8192];     // 32 KB z staging (levels 1..4)
  __shared__ float e_lds[2048];     //  8 KB e-levels 5..8
  __shared__ float lab_lds[512];
  __shared__ float eroot[256];
  __shared__ int   xh[512];

  for (int idx = t; idx < 512; idx += NTHR) lab_lds[idx] = lab1_g[idx];
  if (t < 256) eroot[t] = eroot_g[t];
  __syncthreads();

  float* xO = out;
  float* fO = out + 32768;
  float* uO = out + 65536;
  float* pO = out + 98304;
  float* rO = out + 131072;

  auto run_level = [&](int l, bool isbit) {
    const int rows = 128 >> l;
    const float* W1 = isbit ? Wb1 : Wc1;
    const float* B1 = isbit ? bb1 : bc1;
    const float* W2 = isbit ? Wb2 : Wc2;
    const float* B2 = isbit ? bb2 : bc2;
    const int* u1h = xh + xoff(l);
    const float* zg = nullptr;      // global z (levels 1..4)
    const float* zl = nullptr;      // LDS z
    int zstr = 256;
    float* eoL = nullptr; float* eoG = nullptr;
    switch (l) {
      case 0: zl = eroot; zstr = 0;  eoG = eg + E1_OFF; break;
      case 1: zg = eg + E1_OFF;      eoG = eg + E2_OFF; break;
      case 2: zg = eg + E2_OFF;      eoG = eg + E3_OFF; break;
      case 3: zg = eg + E3_OFF;      eoG = eg + E4_OFF; break;
      case 4: zg = eg + E4_OFF;      eoL = e_lds + ldse(5); break;
      case 5: zl = e_lds + ldse(5);  eoL = e_lds + ldse(6); break;
      case 6: zl = e_lds + ldse(6);  eoL = e_lds + ldse(7); break;
      default: zl = e_lds + ldse(7); eoL = e_lds + ldse(8); break;
    }
    int done = 0;
    while (done < rows) {
      int c = rows - done;
      if (c > 32) c = 32;
      const float* zsrc;
      if (zg) {   // stage global z rows into LDS (coalesced, all in flight)
        const float* src = zg + done * 256;
        const int total = c * 256;
        for (int idx = 4 * t; idx < total; idx += 4 * NTHR)
          *reinterpret_cast<float4*>(z_lds + idx) =
              *reinterpret_cast<const float4*>(src + idx);
        __syncthreads();
        zsrc = z_lds;
      } else {
        zsrc = (zstr == 0) ? zl : zl + done * 256;
      }
      float* eoLc = eoL ? eoL + done * 128 : nullptr;
      float* eoGc = eoG ? eoG + done * 128 : nullptr;
      mlp_chunk(zsrc, zstr, c, W1, B1, W2, B2, lab_lds, isbit, u1h, done,
                red, h_lds, eoLc, eoGc);
      done += c;
    }
  };

  auto do_leaf = [&](int i) {
    const float* e = e_lds + ldse(8);
    if (t < 64) {
      float partial = e[t] * Wl[t] + e[t + 64] * Wl[t + 64];
#pragma unroll
      for (int m = 32; m >= 1; m >>= 1) partial += __shfl_xor(partial, m);
      if (t == 0) {
        const float tv = partial + bl[0];
        const float p  = 1.0f / (1.0f + expf(-tv));
        const float rv = rin[b * 256 + i];
        const int  hd     = (rv > p) ? 1 : 0;
        const bool frozen = fabsf(p - 0.5f) > 0.25f;
        const int  k  = pos2k[i];
        const int  fc = (k >= 0) ? info_bits[b * 128 + k] : 2;
        const int  x  = (fc == 2 || frozen) ? hd : fc;
        xh[xoff(7) + (i & 1)] = x;
        pO[b * 256 + i] = p;
        uO[b * 256 + i] = (float)x;
        fO[b * 256 + i] = (k >= 0) ? 2.0f : 1.0f;
        rO[b * 256 + i] = rv;
      }
    }
    __syncthreads();
  };
  auto do_combine = [&](int l, int side) {
    const int n = 256 >> l, half = n >> 1;
    if (t < half) {
      const int u1 = xh[xoff(l) + t];
      const int u2 = xh[xoff(l) + half + t];
      if (l > 0) {
        const int base = xoff(l - 1) + side * n;
        xh[base + 2 * t]     = u1 ^ u2;
        xh[base + 2 * t + 1] = u2;
      } else {
        xO[b * 256 + 2 * t]     = (float)(u1 ^ u2);
        xO[b * 256 + 2 * t + 1] = (float)u2;
      }
    }
    __syncthreads();
  };

  // ---- SC traversal, single stage call-site ----
  int i = 0, l = 0;
  bool isbit = false;
  while (true) {
    run_level(l, isbit);
    if (l < 7) { ++l; isbit = false; continue; }
    do_leaf(i);
    if (i == 255) break;
    ++i;
    const int s = __builtin_ctz(i);
    for (int j = 1; j <= s; ++j) do_combine(8 - j, (j < s) ? 1 : 0);
    l = 7 - s;
    isbit = true;
  }
  for (int j = 1; j <= 8; ++j) do_combine(8 - j, 1);
}

extern "C" void kernel_launch(void* const* d_in, const int* in_sizes, int n_in,
                              void* d_out, int out_size, void* d_ws, size_t ws_size,
                              hipStream_t stream)
{
  const int*   info_bits = (const int*)  d_in[0];
  const float* rin       = (const float*)d_in[1];
  const int*   info_set  = (const int*)  d_in[2];
  const float* E_obs     = (const float*)d_in[3];
  const float* E_lab     = (const float*)d_in[4];
  const float* Wc1 = (const float*)d_in[5];
  const float* bc1 = (const float*)d_in[6];
  const float* Wc2 = (const float*)d_in[7];
  const float* bc2 = (const float*)d_in[8];
  const float* Wb1 = (const float*)d_in[9];
  const float* bb1 = (const float*)d_in[10];
  const float* Wb2 = (const float*)d_in[11];
  const float* bb2 = (const float*)d_in[12];
  const float* Wl  = (const float*)d_in[13];
  const float* bl  = (const float*)d_in[14];

  int*   pos2k = (int*)d_ws;                 // 256 ints
  float* lab1  = (float*)d_ws + 256;         // 512 floats
  float* eroot = (float*)d_ws + 768;         // 256 floats
  float* wsall = (float*)d_ws + 1024;        // 128 x EG_STRIDE floats

  hipLaunchKernelGGL(sc_setup, dim3(1), dim3(256), 0, stream,
                     info_set, E_obs, E_lab, Wb1, pos2k, lab1, eroot);
  hipLaunchKernelGGL(sc_main, dim3(128), dim3(NTHR), 0, stream,
                     info_bits, rin,
                     Wc1, bc1, Wc2, bc2, Wb1, bb1, Wb2, bb2, Wl, bl,
                     pos2k, lab1, eroot, wsall, (float*)d_out);
}